// Round 6
// baseline (164.984 us; speedup 1.0000x reference)
//
#include <hip/hip_runtime.h>
#include <math.h>

// ---------------- workspace layout (float offsets) ----------------
#define NHEAD     10004
#define OFF_HEAD  0        // 10004 head logits
#define OFF_H0    10004    // 512  projected vec, cluster 0
#define OFF_H1    10516    // 256
#define OFF_H2    10772    // 128
#define OFF_H3    10900    // 64
#define OFF_C0    10964    // 10000 cluster-0 logits
#define OFF_C1    20964    // 20000
#define OFF_C2    40964    // 40000
#define OFF_C3    80964    // 20000
// partial exp-sums, contiguous: head 626 | c0 313 | c1 313 | c2 313 | c3 79
#define OFF_P     100964
#define OFF_PH    100964
#define OFF_P0    101590
#define OFF_P1    101903
#define OFF_P2    102216
#define OFF_P3    102529
#define NPART     1644

__device__ __forceinline__ float wave_sum(float v) {
  v += __shfl_xor(v, 32, 64);
  v += __shfl_xor(v, 16, 64);
  v += __shfl_xor(v, 8, 64);
  v += __shfl_xor(v, 4, 64);
  v += __shfl_xor(v, 2, 64);
  v += __shfl_xor(v, 1, 64);
  return v;
}

__device__ __forceinline__ float dot4(float4 a, float4 c) {
  return a.x * c.x + a.y * c.y + a.z * c.z + a.w * c.w;
}

// Kernel A: the 960 projection rows only (4 MB — fast, unblocks tail).
__global__ __launch_bounds__(256) void proj_kernel(
    const float* __restrict__ feat,
    const float* __restrict__ p0, const float* __restrict__ p1,
    const float* __restrict__ p2, const float* __restrict__ p3,
    float* __restrict__ ws) {
  __shared__ __align__(16) float sf[1024];
  ((float4*)sf)[threadIdx.x] = ((const float4*)feat)[threadIdx.x];
  __syncthreads();
  const float4* sf4 = (const float4*)sf;
  const int wave = threadIdx.x >> 6, lane = threadIdx.x & 63;
  const int pb = blockIdx.x;
#pragma unroll
  for (int k = 0; k < 4; ++k) {
    int row = NHEAD + pb * 16 + wave * 4 + k;  // 10004..10963
    const float* src;
    if (row < 10516)      src = p0 + (size_t)(row - 10004) * 1024;
    else if (row < 10772) src = p1 + (size_t)(row - 10516) * 1024;
    else if (row < 10900) src = p2 + (size_t)(row - 10772) * 1024;
    else                  src = p3 + (size_t)(row - 10900) * 1024;
    const float4* src4 = (const float4*)src;
    float acc = 0.f;
#pragma unroll
    for (int j = 0; j < 4; ++j) acc += dot4(src4[lane + j * 64], sf4[lane + j * 64]);
    acc = wave_sum(acc);
    if (lane == 0) ws[row] = acc;
  }
}

// Kernel B: head + all cluster rows; every block streams exactly 64 KB.
// Blocks: [0,626) head 16r | [626,939) c0 32r | [939,1252) c1 64r
//         [1252,1565) c2 128r | [1565,1644) c3 256r
__global__ __launch_bounds__(256) void main_kernel(
    const float* __restrict__ feat, const float* __restrict__ head_w,
    const float* __restrict__ w0, const float* __restrict__ w1,
    const float* __restrict__ w2, const float* __restrict__ w3,
    float* __restrict__ ws) {
  __shared__ __align__(16) float sh[1024];
  __shared__ float wred[4];
  const int b = blockIdx.x;
  const int wave = threadIdx.x >> 6, lane = threadIdx.x & 63;
  float esum = 0.f;
  int poff, lb;

  if (b < 626) {            // head: 4 rows/wave, D=1024 (4 loads in flight)
    lb = b; poff = OFF_PH;
    ((float4*)sh)[threadIdx.x] = ((const float4*)feat)[threadIdx.x];
    __syncthreads();
    const float4* sf4 = (const float4*)sh;
    const int row0 = lb * 16 + wave * 4;
#pragma unroll
    for (int k = 0; k < 4; ++k) {
      int row = row0 + k;
      int rc = min(row, NHEAD - 1);
      const float4* src4 = (const float4*)head_w + (size_t)rc * 256;
      float acc = 0.f;
#pragma unroll
      for (int j = 0; j < 4; ++j) acc += dot4(src4[lane + j * 64], sf4[lane + j * 64]);
      acc = wave_sum(acc);
      if (lane == 0 && row < NHEAD) { ws[OFF_HEAD + row] = acc; esum += expf(acc); }
    }
  } else if (b < 939) {     // c0: h=512, 8 rows/wave, rows paired (4 loads in flight)
    lb = b - 626; poff = OFF_P0;
    if (threadIdx.x < 128) ((float4*)sh)[threadIdx.x] = ((const float4*)(ws + OFF_H0))[threadIdx.x];
    __syncthreads();
    const float4* sh4 = (const float4*)sh;
    const float4 cv0 = sh4[lane], cv1 = sh4[lane + 64];
    const int row0 = lb * 32 + wave * 8;
#pragma unroll
    for (int k = 0; k < 8; k += 2) {
      int ra = min(row0 + k, 9999), rb = min(row0 + k + 1, 9999);
      const float4* wa = (const float4*)(w0 + (size_t)ra * 512);
      const float4* wb = (const float4*)(w0 + (size_t)rb * 512);
      float sa = dot4(wa[lane], cv0) + dot4(wa[lane + 64], cv1);
      float sb = dot4(wb[lane], cv0) + dot4(wb[lane + 64], cv1);
      sa = wave_sum(sa); sb = wave_sum(sb);
      if (lane == 0) {
        if (row0 + k < 10000)     { ws[OFF_C0 + row0 + k] = sa;     esum += expf(sa); }
        if (row0 + k + 1 < 10000) { ws[OFF_C0 + row0 + k + 1] = sb; esum += expf(sb); }
      }
    }
  } else if (b < 1252) {    // c1: h=256, 16 rows/wave, rows paired
    lb = b - 939; poff = OFF_P1;
    if (threadIdx.x < 64) ((float4*)sh)[threadIdx.x] = ((const float4*)(ws + OFF_H1))[threadIdx.x];
    __syncthreads();
    const float4 cv = ((const float4*)sh)[lane];
    const int row0 = lb * 64 + wave * 16;
#pragma unroll
    for (int k = 0; k < 16; k += 2) {
      int ra = min(row0 + k, 19999), rb = min(row0 + k + 1, 19999);
      float sa = dot4(((const float4*)(w1 + (size_t)ra * 256))[lane], cv);
      float sb = dot4(((const float4*)(w1 + (size_t)rb * 256))[lane], cv);
      sa = wave_sum(sa); sb = wave_sum(sb);
      if (lane == 0) {
        if (row0 + k < 20000)     { ws[OFF_C1 + row0 + k] = sa;     esum += expf(sa); }
        if (row0 + k + 1 < 20000) { ws[OFF_C1 + row0 + k + 1] = sb; esum += expf(sb); }
      }
    }
  } else if (b < 1565) {    // c2: h=128, float4 wave-load covers 2 rows; pairs paired
    lb = b - 1252; poff = OFF_P2;
    if (threadIdx.x < 32) ((float4*)sh)[threadIdx.x] = ((const float4*)(ws + OFF_H2))[threadIdx.x];
    __syncthreads();
    const float4 cv = ((const float4*)sh)[lane & 31];
    const int row0 = lb * 128 + wave * 32;
#pragma unroll
    for (int p = 0; p < 16; p += 2) {
      int r0 = row0 + 2 * p;          // pair A rows r0,r0+1; pair B rows r0+2,r0+3
      int r0c = min(r0, 39998);
      int r1c = min(r0 + 2, 39998);
      float sa = dot4(((const float4*)w2)[(size_t)r0c * 32 + lane], cv);
      float sb = dot4(((const float4*)w2)[(size_t)r1c * 32 + lane], cv);
#pragma unroll
      for (int m = 1; m <= 16; m <<= 1) {
        sa += __shfl_xor(sa, m, 64);
        sb += __shfl_xor(sb, m, 64);
      }
      if ((lane & 31) == 0) {
        int ra = r0 + (lane >> 5), rb2 = r0 + 2 + (lane >> 5);
        if (r0 < 40000)     { ws[OFF_C2 + ra]  = sa; esum += expf(sa); }
        if (r0 + 2 < 40000) { ws[OFF_C2 + rb2] = sb; esum += expf(sb); }
      }
    }
  } else {                  // c3: h=64, float4 wave-load covers 4 rows; quads paired
    lb = b - 1565; poff = OFF_P3;
    if (threadIdx.x < 16) ((float4*)sh)[threadIdx.x] = ((const float4*)(ws + OFF_H3))[threadIdx.x];
    __syncthreads();
    const float4 cv = ((const float4*)sh)[lane & 15];
    const int row0 = lb * 256 + wave * 64;
#pragma unroll
    for (int q = 0; q < 16; q += 2) {
      int ra = row0 + 4 * q, rb = row0 + 4 * (q + 1);
      int rac = min(ra, 19996), rbc = min(rb, 19996);
      float sa = dot4(((const float4*)w3)[(size_t)rac * 16 + lane], cv);
      float sb = dot4(((const float4*)w3)[(size_t)rbc * 16 + lane], cv);
#pragma unroll
      for (int m = 1; m <= 8; m <<= 1) {
        sa += __shfl_xor(sa, m, 64);
        sb += __shfl_xor(sb, m, 64);
      }
      if ((lane & 15) == 0) {
        int g = lane >> 4;
        if (ra < 20000) { ws[OFF_C3 + ra + g] = sa; esum += expf(sa); }
        if (rb < 20000) { ws[OFF_C3 + rb + g] = sb; esum += expf(sb); }
      }
    }
  }
  esum = wave_sum(esum);
  if (lane == 0) wred[wave] = esum;
  __syncthreads();
  if (threadIdx.x == 0) ws[poff + lb] = wred[0] + wred[1] + wred[2] + wred[3];
}

// Kernel C: single 1024-thread block. One-pass 5-accumulator reduction of the
// contiguous partial array, 5 LSEs, gather 4096 targets (4/thread), mean.
__global__ __launch_bounds__(1024) void finalize_kernel(
    const int* __restrict__ targets, float* __restrict__ ws,
    float* __restrict__ out) {
  const int wv = threadIdx.x >> 6, lane = threadIdx.x & 63;
  float a0 = 0.f, a1 = 0.f, a2 = 0.f, a3 = 0.f, a4 = 0.f;
#pragma unroll
  for (int it = 0; it < 2; ++it) {
    int i = threadIdx.x + it * 1024;
    if (i < NPART) {
      float v = ws[OFF_P + i];
      if (i < 626)       a0 += v;
      else if (i < 939)  a1 += v;
      else if (i < 1252) a2 += v;
      else if (i < 1565) a3 += v;
      else               a4 += v;
    }
  }
  a0 = wave_sum(a0); a1 = wave_sum(a1); a2 = wave_sum(a2);
  a3 = wave_sum(a3); a4 = wave_sum(a4);
  __shared__ float r5[16][5];
  __shared__ float slse[5];
  if (lane == 0) { r5[wv][0] = a0; r5[wv][1] = a1; r5[wv][2] = a2; r5[wv][3] = a3; r5[wv][4] = a4; }
  __syncthreads();
  if (threadIdx.x < 5) {
    float s = 0.f;
#pragma unroll
    for (int w = 0; w < 16; ++w) s += r5[w][threadIdx.x];
    slse[threadIdx.x] = logf(s);
  }
  __syncthreads();
  const float lse0 = slse[0], lse1 = slse[1], lse2 = slse[2], lse3 = slse[3], lse4 = slse[4];
  const float g0 = ws[10000] - lse0, g1 = ws[10001] - lse0;
  const float g2 = ws[10002] - lse0, g3 = ws[10003] - lse0;
  float s = 0.f;
#pragma unroll
  for (int it = 0; it < 4; ++it) {
    int t = targets[threadIdx.x + it * 1024];
    float lp;
    if (t < 10000)      lp = ws[OFF_HEAD + t] - lse0;
    else if (t < 20000) lp = ws[OFF_C0 + t - 10000] - lse1 + g0;
    else if (t < 40000) lp = ws[OFF_C1 + t - 20000] - lse2 + g1;
    else if (t < 80000) lp = ws[OFF_C2 + t - 40000] - lse3 + g2;
    else                lp = ws[OFF_C3 + t - 80000] - lse4 + g3;
    s += lp;
  }
  s = wave_sum(s);
  if (lane == 0) r5[wv][0] = s;
  __syncthreads();
  if (threadIdx.x == 0) {
    float tot = 0.f;
#pragma unroll
    for (int w = 0; w < 16; ++w) tot += r5[w][0];
    out[0] = -tot * (1.f / 4096.f);
  }
}

extern "C" void kernel_launch(void* const* d_in, const int* in_sizes, int n_in,
                              void* d_out, int out_size, void* d_ws, size_t ws_size,
                              hipStream_t stream) {
  const float* feat    = (const float*)d_in[0];
  const int*   targets = (const int*)d_in[1];
  const float* head_w  = (const float*)d_in[2];
  const float* t0p = (const float*)d_in[3];
  const float* t0w = (const float*)d_in[4];
  const float* t1p = (const float*)d_in[5];
  const float* t1w = (const float*)d_in[6];
  const float* t2p = (const float*)d_in[7];
  const float* t2w = (const float*)d_in[8];
  const float* t3p = (const float*)d_in[9];
  const float* t3w = (const float*)d_in[10];
  float* ws  = (float*)d_ws;
  float* out = (float*)d_out;

  proj_kernel<<<60, 256, 0, stream>>>(feat, t0p, t1p, t2p, t3p, ws);
  main_kernel<<<1644, 256, 0, stream>>>(feat, head_w, t0w, t1w, t2w, t3w, ws);
  finalize_kernel<<<1, 1024, 0, stream>>>(targets, ws, out);
}